// Round 1
// baseline (261.323 us; speedup 1.0000x reference)
//
#include <hip/hip_runtime.h>
#include <cstddef>
#include <cstdint>

#define LEAKY(s) ((s) >= 0.f ? (s) : 0.1f * (s))

constexpr int PTS    = 4096;   // H*W
constexpr int NBATCH = 32;
constexpr int NM     = 8;      // regions
constexpr int TILE   = 128;    // points per block in kA
constexpr int NTILES = PTS / TILE;  // 32

// ---------------- workspace layout (bytes) ----------------
// xs   : (B,128,8) f32                     @ 0        (131072)
// idx  : (B,128,8) i32                     @ 131072   (131072)
// y4   : (B,4,1024) f32 partial conv_sp    @ 262144   (524288)
// part : (B,128,8,NTILES) f32              @ 786432   (4 MB)   -- consumed by kB
// Dm   : (B,128,8,128) f32                 @ 786432   (16 MB)  -- aliases part (written after kB)
constexpr size_t OFF_XS   = 0;
constexpr size_t OFF_IDX  = 131072;
constexpr size_t OFF_Y4   = 262144;
constexpr size_t OFF_PART = 786432;
constexpr size_t OFF_DM   = 786432;

// ============================================================
// Kernel A: fused conv1(5->128) -> conv2 -> conv3 -> region-masked max partials
// grid (NTILES, B), 256 threads. LDS: act[128][128] + region[8][128]
// ============================================================
__device__ __forceinline__ void gemm128(const float* __restrict__ W,
                                        const float* act, int c0, int pl,
                                        float acc[8][8]) {
#pragma unroll
  for (int i = 0; i < 8; i++)
#pragma unroll
    for (int j = 0; j < 8; j++) acc[i][j] = 0.f;
  for (int k = 0; k < 128; k += 4) {
    float4 wv[8];
#pragma unroll
    for (int i = 0; i < 8; i++) wv[i] = *(const float4*)(W + (c0 + i) * 128 + k);
    float4 bl0[4], bl1[4];
#pragma unroll
    for (int kk = 0; kk < 4; kk++) {
      bl0[kk] = *(const float4*)(act + (k + kk) * TILE + pl);
      bl1[kk] = *(const float4*)(act + (k + kk) * TILE + pl + 4);
    }
#pragma unroll
    for (int kk = 0; kk < 4; kk++) {
      float bv[8] = {bl0[kk].x, bl0[kk].y, bl0[kk].z, bl0[kk].w,
                     bl1[kk].x, bl1[kk].y, bl1[kk].z, bl1[kk].w};
#pragma unroll
      for (int i = 0; i < 8; i++) {
        float w = (kk == 0) ? wv[i].x : (kk == 1) ? wv[i].y : (kk == 2) ? wv[i].z : wv[i].w;
#pragma unroll
        for (int j = 0; j < 8; j++) acc[i][j] = fmaf(w, bv[j], acc[i][j]);
      }
    }
  }
}

__global__ __launch_bounds__(256) void kA(
    const float* __restrict__ coor, const float* __restrict__ region,
    const float* __restrict__ extents,
    const float* __restrict__ w1, const float* __restrict__ b1,
    const float* __restrict__ w2, const float* __restrict__ b2,
    const float* __restrict__ w3, const float* __restrict__ b3,
    float* __restrict__ part) {
  __shared__ float act[128 * TILE];
  __shared__ float reg_s[NM * TILE];
  const int tid = threadIdx.x;
  const int b = blockIdx.y;
  const int t0 = blockIdx.x * TILE;
  const int cg = tid >> 4, pg = tid & 15;
  const int c0 = cg * 8, pl = pg * 8;

  {  // stage region tile: 8 rows x 128
    int m = tid >> 5, j = tid & 31;
    float4 v = *(const float4*)(region + ((size_t)b * NM + m) * PTS + t0 + j * 4);
    *(float4*)(reg_s + m * TILE + j * 4) = v;
  }
  {  // layer 1 (K=5) directly from global
    float e0 = extents[b * 3], e1 = extents[b * 3 + 1], e2 = extents[b * 3 + 2];
    float in[5][8];
#pragma unroll
    for (int i = 0; i < 5; i++) {
      float4 a  = *(const float4*)(coor + ((size_t)b * 5 + i) * PTS + t0 + pl);
      float4 c4 = *(const float4*)(coor + ((size_t)b * 5 + i) * PTS + t0 + pl + 4);
      in[i][0] = a.x;  in[i][1] = a.y;  in[i][2] = a.z;  in[i][3] = a.w;
      in[i][4] = c4.x; in[i][5] = c4.y; in[i][6] = c4.z; in[i][7] = c4.w;
    }
#pragma unroll
    for (int j = 0; j < 8; j++) {
      in[0][j] = (in[0][j] - 0.5f) * e0;
      in[1][j] = (in[1][j] - 0.5f) * e1;
      in[2][j] = (in[2][j] - 0.5f) * e2;
    }
#pragma unroll
    for (int i = 0; i < 8; i++) {
      int c = c0 + i;
      float wA = w1[c * 5], wB = w1[c * 5 + 1], wC = w1[c * 5 + 2],
            wD = w1[c * 5 + 3], wE = w1[c * 5 + 4];
      float bb = b1[c];
      float o[8];
#pragma unroll
      for (int j = 0; j < 8; j++) {
        float s = bb;
        s = fmaf(wA, in[0][j], s); s = fmaf(wB, in[1][j], s); s = fmaf(wC, in[2][j], s);
        s = fmaf(wD, in[3][j], s); s = fmaf(wE, in[4][j], s);
        o[j] = LEAKY(s);
      }
      float4 v0 = {o[0], o[1], o[2], o[3]}, v1 = {o[4], o[5], o[6], o[7]};
      *(float4*)(act + c * TILE + pl) = v0;
      *(float4*)(act + c * TILE + pl + 4) = v1;
    }
  }
  __syncthreads();

  float acc[8][8];
  // layer 2
  gemm128(w2, act, c0, pl, acc);
  __syncthreads();  // everyone done reading act1
#pragma unroll
  for (int i = 0; i < 8; i++) {
    float bb = b2[c0 + i];
    float o[8];
#pragma unroll
    for (int j = 0; j < 8; j++) { float s = acc[i][j] + bb; o[j] = LEAKY(s); }
    float4 v0 = {o[0], o[1], o[2], o[3]}, v1 = {o[4], o[5], o[6], o[7]};
    *(float4*)(act + (c0 + i) * TILE + pl) = v0;
    *(float4*)(act + (c0 + i) * TILE + pl + 4) = v1;
  }
  __syncthreads();
  // layer 3 (no activation)
  gemm128(w3, act, c0, pl, acc);
#pragma unroll
  for (int i = 0; i < 8; i++) {
    float bb = b3[c0 + i];
#pragma unroll
    for (int j = 0; j < 8; j++) acc[i][j] += bb;
  }
  __syncthreads();  // done reading act2; reuse act as scratch [c][m][pg] = c*128 + m*16 + pg

  // region-masked max over this tile's 8 points per thread
#pragma unroll
  for (int m = 0; m < NM; m++) {
#pragma unroll
    for (int i = 0; i < 8; i++) {
      float mx = acc[i][0] * reg_s[m * TILE + pl];
#pragma unroll
      for (int j = 1; j < 8; j++) mx = fmaxf(mx, acc[i][j] * reg_s[m * TILE + pl + j]);
      act[(c0 + i) * 128 + m * 16 + pg] = mx;
    }
  }
  __syncthreads();
  // reduce over 16 point-groups; 1024 (c,m) pairs / 256 threads
#pragma unroll
  for (int q = 0; q < 4; q++) {
    int pair = tid + q * 256;
    int c = pair >> 3, m = pair & 7;
    const float* s = act + c * 128 + m * 16;
    float mx = s[0];
#pragma unroll
    for (int g = 1; g < 16; g++) mx = fmaxf(mx, s[g]);
    part[(((size_t)b * 128 + c) * NM + m) * NTILES + blockIdx.x] = mx;
  }
}

// ============================================================
// Kernel B: reduce partials -> pooled (128,8); softmax over channels per m;
// per-(b,c) descending sort of 8 region values -> idx. grid (B), 256 thr.
// ============================================================
__global__ __launch_bounds__(256) void kB(const float* __restrict__ part,
                                          float* __restrict__ xs,
                                          int* __restrict__ idx) {
  __shared__ float pool[1024];
  __shared__ float xsl[1024];
  int b = blockIdx.x, tid = threadIdx.x;
#pragma unroll
  for (int q = 0; q < 4; q++) {
    int pair = tid + q * 256;
    const float* p = part + (size_t)(b * 1024 + pair) * NTILES;
    float4 v = *(const float4*)p;
    float mx = fmaxf(fmaxf(v.x, v.y), fmaxf(v.z, v.w));
#pragma unroll
    for (int g = 4; g < NTILES; g += 4) {
      float4 u = *(const float4*)(p + g);
      mx = fmaxf(mx, fmaxf(fmaxf(u.x, u.y), fmaxf(u.z, u.w)));
    }
    pool[pair] = mx;
  }
  __syncthreads();
  // softmax over the 128 channels, one 32-lane group per m
  int m = tid >> 5, lane = tid & 31;
  float v[4];
#pragma unroll
  for (int j = 0; j < 4; j++) v[j] = pool[(lane + 32 * j) * 8 + m];
  float mx = fmaxf(fmaxf(v[0], v[1]), fmaxf(v[2], v[3]));
#pragma unroll
  for (int d = 1; d < 32; d <<= 1) mx = fmaxf(mx, __shfl_xor(mx, d, 32));
  float e[4]; float s = 0.f;
#pragma unroll
  for (int j = 0; j < 4; j++) { e[j] = expf(v[j] - mx); s += e[j]; }
#pragma unroll
  for (int d = 1; d < 32; d <<= 1) s += __shfl_xor(s, d, 32);
#pragma unroll
  for (int j = 0; j < 4; j++) {
    float x = e[j] / s;
    int c = lane + 32 * j;
    xsl[c * 8 + m] = x;
    xs[(size_t)b * 1024 + c * 8 + m] = x;
  }
  __syncthreads();
  if (tid < 128) {
    float vv[8];
#pragma unroll
    for (int n = 0; n < 8; n++) vv[n] = xsl[tid * 8 + n];
    int used = 0;
#pragma unroll
    for (int n = 0; n < 8; n++) {
      int best = 0; float bvv = -1.f;
#pragma unroll
      for (int q = 0; q < 8; q++) {
        bool ok = ((used >> q) & 1) == 0;
        if (ok && vv[q] > bvv) { bvv = vv[q]; best = q; }  // strict > == lowest-index tie-break
      }
      used |= 1 << best;
      idx[(size_t)b * 1024 + tid * 8 + n] = best;
    }
  }
}

// ============================================================
// Kernel C: D[b,k,m,o] = sum_c xs[b,c,m] * w_sp[o,c,k]
// grid (32 ktiles of 4, 8 bgroups of 4), 256 thr.
// Per block: rows r = kk*128+o (512), cols = bl*8+m (32), K=c (128, chunks of 16)
// ============================================================
__global__ __launch_bounds__(256) void kC(const float* __restrict__ xs,
                                          const float* __restrict__ w_sp,
                                          float* __restrict__ Dm) {
  __shared__ float As[16 * 512];
  __shared__ float Bs[16 * 32];
  const int tid = threadIdx.x;
  const int k0 = blockIdx.x * 4;
  const int bbase = blockIdx.y * 4;
  const int rg = tid & 63, cgq = tid >> 6;
  const int j0 = cgq * 8;
  float acc[8][8];
#pragma unroll
  for (int i = 0; i < 8; i++)
#pragma unroll
    for (int j = 0; j < 8; j++) acc[i][j] = 0.f;

  for (int c0 = 0; c0 < 128; c0 += 16) {
    __syncthreads();
#pragma unroll
    for (int it = 0; it < 8; it++) {
      int q = tid + it * 256;             // 0..2047
      int o = q >> 4, cc = q & 15;
      float4 w = *(const float4*)(w_sp + (size_t)o * 16384 + (size_t)(c0 + cc) * 128 + k0);
      As[cc * 512 + o]       = w.x;
      As[cc * 512 + 128 + o] = w.y;
      As[cc * 512 + 256 + o] = w.z;
      As[cc * 512 + 384 + o] = w.w;
    }
#pragma unroll
    for (int it = 0; it < 2; it++) {
      int f = tid + it * 256;             // 0..511 = bl*128 + cc*8 + m
      int bl = f >> 7, rem = f & 127;
      Bs[(rem >> 3) * 32 + bl * 8 + (rem & 7)] =
          xs[((size_t)(bbase + bl) * 128 + c0 + (rem >> 3)) * 8 + (rem & 7)];
    }
    __syncthreads();
#pragma unroll
    for (int cc = 0; cc < 16; cc++) {
      float4 a0 = *(const float4*)(As + cc * 512 + rg * 4);        // rows rg*4..+3
      float4 a1 = *(const float4*)(As + cc * 512 + 256 + rg * 4);  // rows 256+rg*4..+3
      float4 p0 = *(const float4*)(Bs + cc * 32 + j0);
      float4 p1 = *(const float4*)(Bs + cc * 32 + j0 + 4);
      float av[8] = {a0.x, a0.y, a0.z, a0.w, a1.x, a1.y, a1.z, a1.w};
      float bv[8] = {p0.x, p0.y, p0.z, p0.w, p1.x, p1.y, p1.z, p1.w};
#pragma unroll
      for (int i = 0; i < 8; i++)
#pragma unroll
        for (int j = 0; j < 8; j++) acc[i][j] = fmaf(av[i], bv[j], acc[i][j]);
    }
  }
#pragma unroll
  for (int j = 0; j < 8; j++) {
    int col = j0 + j;
    int bl = col >> 3, m = col & 7, bb = bbase + bl;
    {
      int r = rg * 4;
      int kk = r >> 7, o = r & 127;
      float4 v = {acc[0][j], acc[1][j], acc[2][j], acc[3][j]};
      *(float4*)(Dm + (((size_t)bb * 128 + k0 + kk) * 8 + m) * 128 + o) = v;
    }
    {
      int r = 256 + rg * 4;
      int kk = r >> 7, o = r & 127;
      float4 v = {acc[4][j], acc[5][j], acc[6][j], acc[7][j]};
      *(float4*)(Dm + (((size_t)bb * 128 + k0 + kk) * 8 + m) * 128 + o) = v;
    }
  }
}

// ============================================================
// Kernel D: partial gather-sum y4[b,kq,o*8+r] = sum_{k in kq} D[b,k,idx[b,k,r],o]
// grid (B, 4), 256 thr.
// ============================================================
__global__ __launch_bounds__(256) void kD(const float* __restrict__ Dm,
                                          const int* __restrict__ idx,
                                          float* __restrict__ y4) {
  __shared__ int il[256];  // 32 k x 8 r
  int b = blockIdx.x, kq = blockIdx.y;
  int tid = threadIdx.x;
  il[tid] = idx[(size_t)b * 1024 + kq * 256 + tid];
  __syncthreads();
  int o = tid & 127, half = tid >> 7;
  const float* Db = Dm + (size_t)b * 131072 + (size_t)kq * 32 * 1024;
  float s0 = 0, s1 = 0, s2 = 0, s3 = 0;
  for (int k = 0; k < 32; k++) {
    const float* Dk = Db + k * 1024;
    const int* ik = il + k * 8 + half * 4;
    s0 += Dk[ik[0] * 128 + o];
    s1 += Dk[ik[1] * 128 + o];
    s2 += Dk[ik[2] * 128 + o];
    s3 += Dk[ik[3] * 128 + o];
  }
  float* yo = y4 + ((size_t)b * 4 + kq) * 1024 + o * 8 + half * 4;
  yo[0] = s0; yo[1] = s1; yo[2] = s2; yo[3] = s3;
}

// ============================================================
// Kernel E: sum kq partials + b_sp + leaky -> fc1 -> fc2 -> heads. grid (B), 256 thr.
// ============================================================
__global__ __launch_bounds__(256) void kE(
    const float* __restrict__ y4, const float* __restrict__ b_sp,
    const float* __restrict__ fc1_w, const float* __restrict__ fc1_b,
    const float* __restrict__ fc2_w, const float* __restrict__ fc2_b,
    const float* __restrict__ fcr_w, const float* __restrict__ fcr_b,
    const float* __restrict__ fct_w, const float* __restrict__ fct_b,
    float* __restrict__ out) {
  __shared__ float yl[1024];
  __shared__ float h1[512];
  __shared__ float h2[256];
  int b = blockIdx.x, tid = threadIdx.x;
  {
    int f0 = tid * 4;
    const float* base = y4 + (size_t)b * 4096;
    float4 a0 = *(const float4*)(base + f0);
    float4 a1 = *(const float4*)(base + 1024 + f0);
    float4 a2 = *(const float4*)(base + 2048 + f0);
    float4 a3 = *(const float4*)(base + 3072 + f0);
    float v[4] = {a0.x + a1.x + a2.x + a3.x, a0.y + a1.y + a2.y + a3.y,
                  a0.z + a1.z + a2.z + a3.z, a0.w + a1.w + a2.w + a3.w};
#pragma unroll
    for (int j = 0; j < 4; j++) {
      int f = f0 + j;
      float s = v[j] + b_sp[f >> 3];
      yl[f] = LEAKY(s);
    }
  }
  __syncthreads();
#pragma unroll
  for (int t = 0; t < 2; t++) {
    int o = tid * 2 + t;
    const float4* wr = (const float4*)(fc1_w + (size_t)o * 1024);
    float sa = 0, sb = 0, sc = 0, sd = 0;
    for (int q = 0; q < 256; q++) {
      float4 w = wr[q];
      float4 u = ((const float4*)yl)[q];
      sa = fmaf(w.x, u.x, sa); sb = fmaf(w.y, u.y, sb);
      sc = fmaf(w.z, u.z, sc); sd = fmaf(w.w, u.w, sd);
    }
    float s = (sa + sb) + (sc + sd) + fc1_b[o];
    h1[o] = LEAKY(s);
  }
  __syncthreads();
  {
    int o = tid;
    const float4* wr = (const float4*)(fc2_w + (size_t)o * 512);
    float sa = 0, sb = 0, sc = 0, sd = 0;
    for (int q = 0; q < 128; q++) {
      float4 w = wr[q];
      float4 u = ((const float4*)h1)[q];
      sa = fmaf(w.x, u.x, sa); sb = fmaf(w.y, u.y, sb);
      sc = fmaf(w.z, u.z, sc); sd = fmaf(w.w, u.w, sd);
    }
    float s = (sa + sb) + (sc + sd) + fc2_b[o];
    h2[o] = LEAKY(s);
  }
  __syncthreads();
  if (tid < 7) {
    bool isrot = tid < 4;
    int o = isrot ? tid : tid - 4;
    const float4* wr = (const float4*)((isrot ? fcr_w : fct_w) + (size_t)o * 256);
    float sa = 0, sb = 0, sc = 0, sd = 0;
    for (int q = 0; q < 64; q++) {
      float4 w = wr[q];
      float4 u = ((const float4*)h2)[q];
      sa = fmaf(w.x, u.x, sa); sb = fmaf(w.y, u.y, sb);
      sc = fmaf(w.z, u.z, sc); sd = fmaf(w.w, u.w, sd);
    }
    float s = (sa + sb) + (sc + sd) + (isrot ? fcr_b[o] : fct_b[o]);
    out[isrot ? (b * 4 + o) : (128 + b * 3 + o)] = s;
  }
}

extern "C" void kernel_launch(void* const* d_in, const int* in_sizes, int n_in,
                              void* d_out, int out_size, void* d_ws, size_t ws_size,
                              hipStream_t stream) {
  const float* coor    = (const float*)d_in[0];
  const float* region  = (const float*)d_in[1];
  const float* extents = (const float*)d_in[2];
  const float* w1 = (const float*)d_in[3];  const float* b1 = (const float*)d_in[4];
  const float* w2 = (const float*)d_in[5];  const float* b2 = (const float*)d_in[6];
  const float* w3 = (const float*)d_in[7];  const float* b3 = (const float*)d_in[8];
  const float* w_sp = (const float*)d_in[9];  const float* b_sp = (const float*)d_in[10];
  const float* fc1_w = (const float*)d_in[11]; const float* fc1_b = (const float*)d_in[12];
  const float* fc2_w = (const float*)d_in[13]; const float* fc2_b = (const float*)d_in[14];
  const float* fcr_w = (const float*)d_in[15]; const float* fcr_b = (const float*)d_in[16];
  const float* fct_w = (const float*)d_in[17]; const float* fct_b = (const float*)d_in[18];

  char* ws = (char*)d_ws;
  float* xs   = (float*)(ws + OFF_XS);
  int*   idx  = (int*)(ws + OFF_IDX);
  float* y4   = (float*)(ws + OFF_Y4);
  float* part = (float*)(ws + OFF_PART);
  float* Dm   = (float*)(ws + OFF_DM);   // aliases part: written only after kB consumed part
  float* out  = (float*)d_out;

  kA<<<dim3(NTILES, NBATCH), 256, 0, stream>>>(coor, region, extents,
                                               w1, b1, w2, b2, w3, b3, part);
  kB<<<dim3(NBATCH), 256, 0, stream>>>(part, xs, idx);
  kC<<<dim3(32, 8), 256, 0, stream>>>(xs, w_sp, Dm);
  kD<<<dim3(NBATCH, 4), 256, 0, stream>>>(Dm, idx, y4);
  kE<<<dim3(NBATCH), 256, 0, stream>>>(y4, b_sp, fc1_w, fc1_b, fc2_w, fc2_b,
                                       fcr_w, fcr_b, fct_w, fct_b, out);
}